// Round 1
// baseline (300.938 us; speedup 1.0000x reference)
//
#include <hip/hip_runtime.h>
#include <hip/hip_bf16.h>
#include <math.h>

// IntentionHeads R9: both heads fused per block, BK=64, 64x128 tile/wave.
//   R8 (129us kernel) was latency-bound: all pipes <45% (Mfma 11, VALU 34,
//   HBM 13%), 6x over the 22us HBM floor. Cause: 2 blocks per token tile
//   (X cvt+staging done twice), 16 barrier intervals with only 16 MFMA each,
//   depth-1 X prefetch vs ~900cy HBM latency.
// R9 structure:
//   - grid 1024: one block = 64 tokens x BOTH heads (512 cols). X staged+
//     converted once. Wc[512][512] rows 0-255 vehicle / 256-511 ped already
//     stacked by prep, so col index == Wc row.
//   - BK=64: 8 K-iters, one barrier each; per wave 64 MFMA/interval (4x R8).
//   - acc[4][8] f32x4 (128 VGPR); W1-frag ping-pong prefetch (next kc-step
//     issued before current MFMA batch); X loads at iter top, LDS write at
//     iter bottom (T14 issue-early/write-late).
//   - X staging fully coalesced: instr u reads contiguous 1KB (lane i ->
//     base + 16B*i), rows u*16+(tid>>4), 16B chunk tid&15.
//   - H [64][512] bf16 in 64KB LDS with XOR swizzle byte^=(row&7)<<4
//     (G4/T2): bank-optimal b128 reads, no pad, exactly 65536B -> 2 blk/CU.
//   - single-writer epilogue: each token's 6 logits + 2 masks from one wave.

#define TOKENS 65536
#define DIM    512
#define HID    256
#define ASTR   72     // X staging row stride in bf16 (64 + 8 pad, 16B mult)
#define NITER  8      // DIM / 64

using short8 = __attribute__((ext_vector_type(8))) short;  // 8 x bf16
using f32x4  = __attribute__((ext_vector_type(4))) float;

// packed RNE f32->bf16 pair (v_perm byte-pack)
__device__ __forceinline__ unsigned int pkrne(float a, float b) {
    unsigned int ua = __float_as_uint(a);
    unsigned int ub = __float_as_uint(b);
    ua += 0x7FFFu + ((ua >> 16) & 1u);
    ub += 0x7FFFu + ((ub >> 16) & 1u);
    return __builtin_amdgcn_perm(ub, ua, 0x07060302u);  // [ua.hi16, ub.hi16]
}

__device__ __forceinline__ uint2 cvt4(f32x4 v) {
    return make_uint2(pkrne(v[0], v[1]), pkrne(v[2], v[3]));
}

__device__ __forceinline__ __hip_bfloat16 bf16rne(float x) {
    unsigned int u = __float_as_uint(x);
    u += 0x7FFFu + ((u >> 16) & 1u);
    unsigned short hs = (unsigned short)(u >> 16);
    return *(__hip_bfloat16*)&hs;
}

__device__ __forceinline__ float gelu_exact(float x) {
    // exact (erf) GELU, matches jax.nn.gelu(approximate=False)
    return 0.5f * x * (1.0f + erff(x * 0.7071067811865475f));
}

// ---------------- prep: weights f32 -> bf16 in workspace --------------------
// Wc  [512][512]: rows 0-255 vW1, 256-511 pW1
// W2c [32][256]:  rows 0-5 vW2, 6-15 zero, 16-17 pW2, 18-31 zero
__global__ __launch_bounds__(256)
void prep_kernel(const float* __restrict__ vW1, const float* __restrict__ pW1,
                 const float* __restrict__ vW2, const float* __restrict__ pW2,
                 __hip_bfloat16* __restrict__ Wc, __hip_bfloat16* __restrict__ W2c)
{
    const int i = blockIdx.x * 256 + threadIdx.x;   // f32x4 chunk index
    if (i < 65536) {                                // W1: 262144 elems
        const int flat = i * 4;
        f32x4 v = (flat < 131072) ? *(const f32x4*)(vW1 + flat)
                                  : *(const f32x4*)(pW1 + flat - 131072);
        *(uint2*)(Wc + flat) = cvt4(v);
    } else if (i < 65536 + 2048) {                  // W2c: 8192 elems
        const int flat = (i - 65536) * 4;
        const int row = flat >> 8, col = flat & 255;
        f32x4 v = (f32x4){0.f, 0.f, 0.f, 0.f};
        if (row < 6)                      v = *(const f32x4*)(vW2 + row * HID + col);
        else if (row >= 16 && row < 18)   v = *(const f32x4*)(pW2 + (row - 16) * HID + col);
        *(uint2*)(W2c + flat) = cvt4(v);
    }
}

// ---------------- main ------------------------------------------------------
__global__ __launch_bounds__(256, 2)
void intention_heads_kernel(const float* __restrict__ X,
                            const int* __restrict__ ids,
                            const __hip_bfloat16* __restrict__ Wc,
                            const __hip_bfloat16* __restrict__ W2c,
                            const float* __restrict__ vb1,
                            const float* __restrict__ pb1,
                            const float* __restrict__ vb2,
                            const float* __restrict__ pb2,
                            float* __restrict__ out)
{
    // LDS union: X staging A0/A1 (2 x 64x72 bf16 = 18KB) then H 64x512 bf16
    // XOR-swizzled (65536B exactly). 64KB -> 2 blocks/CU.
    __shared__ __align__(16) unsigned char smem[65536];
    char* A0 = (char*)smem;
    char* A1 = (char*)smem + 64 * ASTR * 2;

    const int row0 = blockIdx.x * 64;
    const int tid  = threadIdx.x;
    const int wave = tid >> 6;         // 0..3 -> cols wave*128 (both heads)
    const int lane = tid & 63;
    const int quad = lane >> 4;
    const int l16  = lane & 15;
    const int colbase = wave * 128;    // cols 0-255 vehicle, 256-511 ped

    // ---- X staging map: instr u covers rows u*16+(tid>>4), chunk tid&15 ----
    const int srow = tid >> 4;         // 0..15
    const int scol = tid & 15;         // 16B (4-float) chunk within row
    const float* Xb = X + (long)(row0 + srow) * DIM + scol * 4;
    const int wb = srow * (ASTR * 2) + scol * 8;   // LDS byte; +u*2304/row grp

    // ---- W1 fragment per-lane byte offsets (col == Wc row) ----
    const char* Wq = (const char*)Wc;
    int voff[8];
    #pragma unroll
    for (int j = 0; j < 8; ++j)
        voff[j] = (colbase + j * 16 + l16) * (DIM * 2) + quad * 16;

    const int abase = l16 * (ASTR * 2) + quad * 16;

    f32x4 acc[4][8];
    #pragma unroll
    for (int i = 0; i < 4; ++i)
        #pragma unroll
        for (int j = 0; j < 8; ++j)
            acc[i][j] = (f32x4){0.f, 0.f, 0.f, 0.f};

    // ---- prologue: stage X tile 0, load B frags (it0, kc0) ----
    {
        f32x4 x0 = *(const f32x4*)(Xb);
        f32x4 x1 = *(const f32x4*)(Xb + 16 * DIM);
        f32x4 x2 = *(const f32x4*)(Xb + 32 * DIM);
        f32x4 x3 = *(const f32x4*)(Xb + 48 * DIM);
        *(uint2*)(A0 + wb)            = cvt4(x0);
        *(uint2*)(A0 + wb + 2304)     = cvt4(x1);
        *(uint2*)(A0 + wb + 2 * 2304) = cvt4(x2);
        *(uint2*)(A0 + wb + 3 * 2304) = cvt4(x3);
    }
    short8 ba[8];
    #pragma unroll
    for (int j = 0; j < 8; ++j)
        ba[j] = *(const short8*)(Wq + voff[j]);
    __syncthreads();

    // ---- K loop: 8 iters, BK=64 (2 kc sub-steps), one barrier each ----
    #pragma unroll
    for (int it = 0; it < NITER; ++it) {
        char* cur = (it & 1) ? A1 : A0;
        char* nxt = (it & 1) ? A0 : A1;

        // issue kc=1 B frags for this iter (cover: kc0 ds_reads + 32 MFMA)
        short8 bb[8];
        #pragma unroll
        for (int j = 0; j < 8; ++j)
            bb[j] = *(const short8*)(Wq + voff[j] + it * 128 + 64);

        // issue next X tile loads (consumed at iter bottom: ~full-iter cover)
        f32x4 n0, n1, n2, n3;
        if (it < NITER - 1) {
            const float* Xi = Xb + (it + 1) * 64;
            n0 = *(const f32x4*)(Xi);
            n1 = *(const f32x4*)(Xi + 16 * DIM);
            n2 = *(const f32x4*)(Xi + 32 * DIM);
            n3 = *(const f32x4*)(Xi + 48 * DIM);
        }

        // kc = 0
        short8 af[4];
        #pragma unroll
        for (int i = 0; i < 4; ++i)
            af[i] = *(const short8*)(cur + abase + i * 2304);
        #pragma unroll
        for (int i = 0; i < 4; ++i)
            #pragma unroll
            for (int j = 0; j < 8; ++j)
                acc[i][j] = __builtin_amdgcn_mfma_f32_16x16x32_bf16(af[i], ba[j], acc[i][j], 0, 0, 0);

        // issue (it+1, kc0) B frags (cover: kc1 ds_reads + 32 MFMA + barrier)
        if (it < NITER - 1) {
            #pragma unroll
            for (int j = 0; j < 8; ++j)
                ba[j] = *(const short8*)(Wq + voff[j] + (it + 1) * 128);
        }

        // kc = 1
        short8 ag[4];
        #pragma unroll
        for (int i = 0; i < 4; ++i)
            ag[i] = *(const short8*)(cur + abase + i * 2304 + 64);
        #pragma unroll
        for (int i = 0; i < 4; ++i)
            #pragma unroll
            for (int j = 0; j < 8; ++j)
                acc[i][j] = __builtin_amdgcn_mfma_f32_16x16x32_bf16(ag[i], bb[j], acc[i][j], 0, 0, 0);

        // write staged tile (T14 write-late)
        if (it < NITER - 1) {
            *(uint2*)(nxt + wb)            = cvt4(n0);
            *(uint2*)(nxt + wb + 2304)     = cvt4(n1);
            *(uint2*)(nxt + wb + 2 * 2304) = cvt4(n2);
            *(uint2*)(nxt + wb + 3 * 2304) = cvt4(n3);
        }
        __syncthreads();
    }

    // ------------- bias + GELU, stage H [64][512] bf16 XOR-swizzled -------
    const float* b1p = (colbase < HID) ? vb1 : pb1;
    const int cb = colbase & (HID - 1);
    float b1v[8];
    #pragma unroll
    for (int j = 0; j < 8; ++j)
        b1v[j] = b1p[cb + j * 16 + l16];

    #pragma unroll
    for (int i = 0; i < 4; ++i) {
        #pragma unroll
        for (int j = 0; j < 8; ++j) {
            const int col2 = (colbase + j * 16 + l16) * 2;
            #pragma unroll
            for (int rr = 0; rr < 4; ++rr) {
                const int row = i * 16 + quad * 4 + rr;
                const int byte = ((row << 10) + col2) ^ ((row & 7) << 4);
                *(__hip_bfloat16*)((char*)smem + byte) =
                    bf16rne(gelu_exact(acc[i][j][rr] + b1v[j]));
            }
        }
    }
    __syncthreads();

    // ------------- layer 2: both heads, wave handles 16 tokens ------------
    const int tokb = wave * 16;
    const int rowH = tokb + l16;
    const int hb   = (rowH << 10) + quad * 16;
    const int hx   = (rowH & 7) << 4;

    const char* w2v = (const char*)(W2c + l16 * HID) + quad * 16;
    const char* w2p = (const char*)(W2c + (16 + l16) * HID) + quad * 16;

    f32x4 acc2v = (f32x4){0.f, 0.f, 0.f, 0.f};
    f32x4 acc2p = (f32x4){0.f, 0.f, 0.f, 0.f};
    #pragma unroll
    for (int k = 0; k < 8; ++k) {          // vehicle: H cols 0..255
        short8 hv = *(const short8*)((char*)smem + ((hb + k * 64) ^ hx));
        short8 wv = *(const short8*)(w2v + k * 64);
        acc2v = __builtin_amdgcn_mfma_f32_16x16x32_bf16(hv, wv, acc2v, 0, 0, 0);
    }
    #pragma unroll
    for (int k = 0; k < 8; ++k) {          // ped: H cols 256..511 (+512B)
        short8 hp = *(const short8*)((char*)smem + ((hb + 512 + k * 64) ^ hx));
        short8 wp = *(const short8*)(w2p + k * 64);
        acc2p = __builtin_amdgcn_mfma_f32_16x16x32_bf16(hp, wp, acc2p, 0, 0, 0);
    }

    // ------------- single-writer masked epilogue --------------------------
    const float b2v = (l16 < 6) ? vb2[l16] : 0.0f;
    const float b2p = (l16 < 2) ? pb2[l16] : 0.0f;

    #pragma unroll
    for (int rr = 0; rr < 4; ++rr) {
        const int t = row0 + tokb + quad * 4 + rr;
        const int type = ids[t];
        if (l16 == 0) {
            out[TOKENS * 6 + t] = (type == 1) ? 1.0f : 0.0f;
            out[TOKENS * 7 + t] = (type == 2) ? 1.0f : 0.0f;
        }
        if (l16 < 6) {
            float v = 0.0f;
            if (type == 1)                       v = acc2v[rr] + b2v;
            else if (type == 2 && l16 < 2)       v = acc2p[rr] + b2p;
            out[t * 6 + l16] = v;               // types 0,3 and ped pad -> 0
        }
    }
}

extern "C" void kernel_launch(void* const* d_in, const int* in_sizes, int n_in,
                              void* d_out, int out_size, void* d_ws, size_t ws_size,
                              hipStream_t stream) {
    (void)n_in; (void)out_size; (void)ws_size;
    const float* X   = (const float*)d_in[0];
    const int*   ids = (const int*)d_in[1];
    const float* vW1 = (const float*)d_in[2];
    const float* vb1 = (const float*)d_in[3];
    const float* vW2 = (const float*)d_in[4];
    const float* vb2 = (const float*)d_in[5];
    const float* pW1 = (const float*)d_in[6];
    const float* pb1 = (const float*)d_in[7];
    const float* pW2 = (const float*)d_in[8];
    const float* pb2 = (const float*)d_in[9];
    float* out = (float*)d_out;

    // workspace: Wc [512*512] bf16 (512KB) ++ W2c [32*256] bf16 (16KB)
    __hip_bfloat16* Wc  = (__hip_bfloat16*)d_ws;
    __hip_bfloat16* W2c = Wc + 512 * DIM;

    hipLaunchKernelGGL(prep_kernel, dim3(264), dim3(256), 0, stream,
                       vW1, pW1, vW2, pW2, Wc, W2c);

    const int tokens = in_sizes[1];            // 65536
    const int grid   = tokens / 64;            // 1024: one block per 64 tokens

    hipLaunchKernelGGL(intention_heads_kernel, dim3(grid), dim3(256), 0, stream,
                       X, ids, Wc, W2c, vb1, pb1, vb2, pb2, out);
}

// Round 2
// 282.775 us; speedup vs baseline: 1.0642x; 1.0642x over previous
//
#include <hip/hip_runtime.h>
#include <hip/hip_bf16.h>
#include <math.h>

// IntentionHeads R10: R8 geometry + global_load_lds f32 X staging, BK=64.
//   R9 post-mortem: fusing heads into 64KB-LDS/256-reg blocks halved
//   occupancy (16->8 waves/CU) and every counter halved with it -> 241us.
//   Latency cover comes from TLP here; never trade it away.
//   R8 (129us) critical path per K-iter: global->reg, cvt, ds_write,
//   barrier, ds_read = vmcnt+VALU+lgkm serialization each iter.
// R10:
//   - geometry back to R8: 2048 blocks (64 tok x head), 256 thr, 4 blk/CU,
//     acc[4][4] (64 AGPR), LDS 33.8KB (2x16KB f32 X staging | 64x264 H).
//   - X staged as *f32* via __builtin_amdgcn_global_load_lds width 16
//     (m97 lever): no reg round-trip, no staging cvt, loads in flight
//     across the whole iter, drained once at the end-of-iter barrier.
//   - BK=64: 8 iters, 8 barriers (half of R8), 32 MFMA/wave/interval.
//   - f32->bf16 RNE (pkrne) moved to LDS-read side; same accumulation
//     order as R8 -> identical numerics.
//   - X-tile LDS is linear for global_load_lds (m104); bank conflicts on
//     256B-stride row reads fixed by pre-swizzling the *global source*
//     chunk index (rule 21 / m173): chunk ^= (row&7), read addr ^ (row&7)<<4.
//   - T1 bijective XCD swizzle (2048%8==0): vehicle/ped pair + neighbor
//     token tiles share X within one XCD's L2.

#define TOKENS 65536
#define DIM    512
#define HID    256
#define HSTR   264   // H row stride in bf16 (256 + 8 pad, 16B mult)
#define NITER  8     // DIM / 64

using short8 = __attribute__((ext_vector_type(8))) short;  // 8 x bf16
using f32x4  = __attribute__((ext_vector_type(4))) float;

// packed RNE f32->bf16 pair (v_perm byte-pack)
__device__ __forceinline__ unsigned int pkrne(float a, float b) {
    unsigned int ua = __float_as_uint(a);
    unsigned int ub = __float_as_uint(b);
    ua += 0x7FFFu + ((ua >> 16) & 1u);
    ub += 0x7FFFu + ((ub >> 16) & 1u);
    return __builtin_amdgcn_perm(ub, ua, 0x07060302u);  // [ua.hi16, ub.hi16]
}

__device__ __forceinline__ uint2 cvt4(f32x4 v) {
    return make_uint2(pkrne(v[0], v[1]), pkrne(v[2], v[3]));
}

__device__ __forceinline__ __hip_bfloat16 bf16rne(float x) {
    unsigned int u = __float_as_uint(x);
    u += 0x7FFFu + ((u >> 16) & 1u);
    unsigned short hs = (unsigned short)(u >> 16);
    return *(__hip_bfloat16*)&hs;
}

__device__ __forceinline__ float gelu_exact(float x) {
    // exact (erf) GELU, matches jax.nn.gelu(approximate=False)
    return 0.5f * x * (1.0f + erff(x * 0.7071067811865475f));
}

// ---------------- prep: weights f32 -> bf16 in workspace --------------------
// Wc  [512][512]: rows 0-255 vW1, 256-511 pW1
// W2c [32][256]:  rows 0-5 vW2, 6-15 zero, 16-17 pW2, 18-31 zero
__global__ __launch_bounds__(256)
void prep_kernel(const float* __restrict__ vW1, const float* __restrict__ pW1,
                 const float* __restrict__ vW2, const float* __restrict__ pW2,
                 __hip_bfloat16* __restrict__ Wc, __hip_bfloat16* __restrict__ W2c)
{
    const int i = blockIdx.x * 256 + threadIdx.x;   // f32x4 chunk index
    if (i < 65536) {                                // W1: 262144 elems
        const int flat = i * 4;
        f32x4 v = (flat < 131072) ? *(const f32x4*)(vW1 + flat)
                                  : *(const f32x4*)(pW1 + flat - 131072);
        *(uint2*)(Wc + flat) = cvt4(v);
    } else if (i < 65536 + 2048) {                  // W2c: 8192 elems
        const int flat = (i - 65536) * 4;
        const int row = flat >> 8, col = flat & 255;
        f32x4 v = (f32x4){0.f, 0.f, 0.f, 0.f};
        if (row < 6)                      v = *(const f32x4*)(vW2 + row * HID + col);
        else if (row >= 16 && row < 18)   v = *(const f32x4*)(pW2 + (row - 16) * HID + col);
        *(uint2*)(W2c + flat) = cvt4(v);
    }
}

// ---------------- main ------------------------------------------------------
__global__ __launch_bounds__(256, 3)
void intention_heads_kernel(const float* __restrict__ X,
                            const int* __restrict__ ids,
                            const __hip_bfloat16* __restrict__ Wc,
                            const __hip_bfloat16* __restrict__ W2c,
                            const float* __restrict__ vb1,
                            const float* __restrict__ pb1,
                            const float* __restrict__ vb2,
                            const float* __restrict__ pb2,
                            float* __restrict__ out)
{
    // LDS union: X f32 staging A0/A1 (2 x 64x64xf32 = 32KB, LINEAR for
    // global_load_lds) then H 64x264 bf16 (33.8KB). 33792 B -> 4 blk/CU.
    __shared__ __align__(16) unsigned char smem[64 * HSTR * 2];
    __hip_bfloat16* H = (__hip_bfloat16*)smem;

    // T1 bijective XCD swizzle: each XCD gets a contiguous 256-block chunk
    // (= 8192 contiguous tokens x both heads) -> X shared in its L2.
    const int cpx = gridDim.x >> 3;                 // 256 for grid 2048
    const int bid = (blockIdx.x & 7) * cpx + (blockIdx.x >> 3);

    const int head = bid & 1;           // 0 = vehicle, 1 = pedestrian
    const int row0 = (bid >> 1) * 64;

    const int tid  = threadIdx.x;
    const int wave = tid >> 6;          // 0..3 -> hidden cols wave*64
    const int lane = tid & 63;
    const int quad = lane >> 4;
    const int l16  = lane & 15;
    const int wcol = wave * 64;

    // ---- X staging map (global_load_lds): wave issues 4 instrs; instr u
    // covers seg=wave*4+u -> rows seg*4..seg*4+3, each row 256B of K.
    // LDS dest linear: byte = seg*1024 + lane*16 (== row*256 + chunk*16).
    // Source chunk pre-swizzled: chunk_g = chunk ^ (row&7), so the read
    // side uses addr ^ ((row&7)<<4) for conflict-free b128 reads.
    const int srowL  = lane >> 4;       // row within seg (0..3)
    const int schunk = lane & 15;       // 16B chunk within row's 256B

    // ---- W1 fragment byte offsets (bf16 weights, row-major [n][k]) ----
    const char* Wq = (const char*)Wc;
    int boff[4];
    #pragma unroll
    for (int j = 0; j < 4; ++j)
        boff[j] = (head * 256 + wcol + j * 16 + l16) * (DIM * 2) + quad * 16;

    f32x4 acc[4][4];
    #pragma unroll
    for (int i = 0; i < 4; ++i)
        #pragma unroll
        for (int j = 0; j < 4; ++j)
            acc[i][j] = (f32x4){0.f, 0.f, 0.f, 0.f};

    #define STAGE(bufoff, itv)                                               \
    {                                                                        \
        _Pragma("unroll")                                                    \
        for (int u = 0; u < 4; ++u) {                                        \
            const int seg = wave * 4 + u;                                    \
            const int row = seg * 4 + srowL;                                 \
            const int chg = schunk ^ (row & 7);                              \
            const float* gsrc = X + (long)(row0 + row) * DIM                 \
                                + (itv) * 64 + chg * 4;                      \
            __builtin_amdgcn_global_load_lds((const void*)gsrc,              \
                (void*)(smem + (bufoff) + seg * 1024), 16, 0, 0);            \
        }                                                                    \
    }

    // ---- prologue: stage tile 0, load B frags (it0, kc0) ----
    STAGE(0, 0);
    short8 ba[4], bb[4];
    #pragma unroll
    for (int j = 0; j < 4; ++j)
        ba[j] = *(const short8*)(Wq + boff[j]);
    __syncthreads();   // tile 0 landed

    // ---- K loop: 8 iters, BK=64 (2 kc sub-steps), one barrier each ----
    #pragma unroll 2
    for (int it = 0; it < NITER; ++it) {
        const int curo = (it & 1) ? 16384 : 0;
        const int nxto = (it & 1) ? 0 : 16384;

        // issue next tile's async loads (in flight across this whole iter;
        // target buffer was released by the previous barrier)
        if (it < NITER - 1)
            STAGE(nxto, it + 1);
        // this iter's kc=1 B frags (cover: kc0 ds_reads + 16 MFMA)
        #pragma unroll
        for (int j = 0; j < 4; ++j)
            bb[j] = *(const short8*)(Wq + boff[j] + it * 128 + 64);

        // kc = 0: read f32 frags (swizzled addr), cvt, MFMA
        #pragma unroll
        for (int i = 0; i < 4; ++i) {
            const int row = i * 16 + l16;
            const int lin = row * 256 + quad * 32;
            const int sw  = (row & 7) << 4;
            f32x4 xa = *(const f32x4*)(smem + curo + (lin ^ sw));
            f32x4 xb = *(const f32x4*)(smem + curo + ((lin + 16) ^ sw));
            union { short8 s; uint2 u[2]; } f;
            f.u[0] = cvt4(xa); f.u[1] = cvt4(xb);
            #pragma unroll
            for (int j = 0; j < 4; ++j)
                acc[i][j] = __builtin_amdgcn_mfma_f32_16x16x32_bf16(f.s, ba[j], acc[i][j], 0, 0, 0);
        }

        // next iter's kc=0 B frags (cover: kc1 ds_reads + 16 MFMA + barrier)
        if (it < NITER - 1) {
            #pragma unroll
            for (int j = 0; j < 4; ++j)
                ba[j] = *(const short8*)(Wq + boff[j] + (it + 1) * 128);
        }

        // kc = 1
        #pragma unroll
        for (int i = 0; i < 4; ++i) {
            const int row = i * 16 + l16;
            const int lin = row * 256 + 128 + quad * 32;
            const int sw  = (row & 7) << 4;
            f32x4 xa = *(const f32x4*)(smem + curo + (lin ^ sw));
            f32x4 xb = *(const f32x4*)(smem + curo + ((lin + 16) ^ sw));
            union { short8 s; uint2 u[2]; } f;
            f.u[0] = cvt4(xa); f.u[1] = cvt4(xb);
            #pragma unroll
            for (int j = 0; j < 4; ++j)
                acc[i][j] = __builtin_amdgcn_mfma_f32_16x16x32_bf16(f.s, bb[j], acc[i][j], 0, 0, 0);
        }

        __syncthreads();   // vmcnt drain: next tile landed, cur released
    }
    #undef STAGE

    // ------------- bias + GELU, stage H tile (bf16) -----------------------
    const float* b1 = head ? pb1 : vb1;
    float b1v[4];
    #pragma unroll
    for (int j = 0; j < 4; ++j)
        b1v[j] = b1[wcol + j * 16 + l16];

    #pragma unroll
    for (int i = 0; i < 4; ++i) {
        #pragma unroll
        for (int j = 0; j < 4; ++j) {
            const int col = wcol + j * 16 + l16;
            #pragma unroll
            for (int rr = 0; rr < 4; ++rr) {
                const int row = i * 16 + quad * 4 + rr;
                H[row * HSTR + col] = bf16rne(gelu_exact(acc[i][j][rr] + b1v[j]));
            }
        }
    }
    __syncthreads();

    // ------------- layer 2: H[64x256] @ W2^T (zero-padded to 16) ----------
    const float* b2 = head ? pb2 : vb2;
    const int nOut = head ? 2 : 6;

    f32x4 acc2 = (f32x4){0.f, 0.f, 0.f, 0.f};
    const int tokb = wave * 16;
    const short* hbase  = (const short*)&H[(tokb + l16) * HSTR + quad * 8];
    const __hip_bfloat16* w2base = W2c + (head * 16 + l16) * HID + quad * 8;
    #pragma unroll
    for (int k0 = 0; k0 < HID; k0 += 32) {
        short8 af    = *(const short8*)(hbase + k0);
        short8 bfrag = *(const short8*)(w2base + k0);   // zero rows pad n>=nOut
        acc2 = __builtin_amdgcn_mfma_f32_16x16x32_bf16(af, bfrag, acc2, 0, 0, 0);
    }

    // ------------- masked epilogue (f32 writes) ---------------------------
    const float b2v = (l16 < nOut) ? b2[l16] : 0.0f;

    #pragma unroll
    for (int rr = 0; rr < 4; ++rr) {
        const int t = row0 + tokb + quad * 4 + rr;
        const int type = ids[t];
        if (head == 0) {
            if (l16 == 0) {
                out[TOKENS * 6 + t] = (type == 1) ? 1.0f : 0.0f;
                out[TOKENS * 7 + t] = (type == 2) ? 1.0f : 0.0f;
            }
            if (l16 < 6) {
                if (type == 1)
                    out[t * 6 + l16] = acc2[rr] + b2v;
                else if (type != 2)
                    out[t * 6 + l16] = 0.0f;        // types 0,3 -> zeros
                // type==2 slots written by the pedestrian block
            }
        } else {
            if (l16 < 6 && type == 2)
                out[t * 6 + l16] = (l16 < 2) ? (acc2[rr] + b2v) : 0.0f;
        }
    }
}

extern "C" void kernel_launch(void* const* d_in, const int* in_sizes, int n_in,
                              void* d_out, int out_size, void* d_ws, size_t ws_size,
                              hipStream_t stream) {
    (void)n_in; (void)out_size; (void)ws_size;
    const float* X   = (const float*)d_in[0];
    const int*   ids = (const int*)d_in[1];
    const float* vW1 = (const float*)d_in[2];
    const float* vb1 = (const float*)d_in[3];
    const float* vW2 = (const float*)d_in[4];
    const float* vb2 = (const float*)d_in[5];
    const float* pW1 = (const float*)d_in[6];
    const float* pb1 = (const float*)d_in[7];
    const float* pW2 = (const float*)d_in[8];
    const float* pb2 = (const float*)d_in[9];
    float* out = (float*)d_out;

    // workspace: Wc [512*512] bf16 (512KB) ++ W2c [32*256] bf16 (16KB)
    __hip_bfloat16* Wc  = (__hip_bfloat16*)d_ws;
    __hip_bfloat16* W2c = Wc + 512 * DIM;

    hipLaunchKernelGGL(prep_kernel, dim3(264), dim3(256), 0, stream,
                       vW1, pW1, vW2, pW2, Wc, W2c);

    const int tokens = in_sizes[1];            // 65536
    const int grid   = (tokens / 64) * 2;      // token-tile x head

    hipLaunchKernelGGL(intention_heads_kernel, dim3(grid), dim3(256), 0, stream,
                       X, ids, Wc, W2c, vb1, pb1, vb2, pb2, out);
}